// Round 1
// 1102.853 us; speedup vs baseline: 1.0581x; 1.0581x over previous
//
#include <hip/hip_runtime.h>
#include <cstddef>

// Problem constants
#define B_    128
#define V_    512
#define DIN_  511
#define DOUT_ 256
#define DEPTH_ 8

typedef float f32x4 __attribute__((ext_vector_type(4)));

// ---------------- kernel 1: fused softmax + base ----------------
// grid = DEPTH*3, 256 threads. Each block recomputes softmax(L[i]) locally
// (cheap: 512 loads + 2 wave-reduces), so no separate softmax kernel / no
// inter-kernel dependency. part 0/1: baseH columns, part 2: baseF + store W.
__global__ void __launch_bounds__(256)
k_prep(const float* __restrict__ L, const float* __restrict__ vu,
       const float* __restrict__ vfs,
       float* __restrict__ W, float* __restrict__ baseH, float* __restrict__ baseF) {
    const int bx = blockIdx.x;
    const int i = bx / 3, part = bx % 3;
    const int t = threadIdx.x;
    const int lane = t & 63, wid = t >> 6;
    __shared__ float Wl[V_];
    __shared__ float red[4];

    float x0 = L[i * V_ + t];
    float x1 = L[i * V_ + 256 + t];

    // max reduce (wave butterfly + 4-wave combine)
    float m = fmaxf(x0, x1);
    #pragma unroll
    for (int off = 32; off; off >>= 1) m = fmaxf(m, __shfl_xor(m, off, 64));
    if (lane == 0) red[wid] = m;
    __syncthreads();
    const float mx = fmaxf(fmaxf(red[0], red[1]), fmaxf(red[2], red[3]));

    float e0 = expf(x0 - mx), e1 = expf(x1 - mx);
    float s = e0 + e1;
    #pragma unroll
    for (int off = 32; off; off >>= 1) s += __shfl_xor(s, off, 64);
    __syncthreads();                 // all reads of red done before reuse
    if (lane == 0) red[wid] = s;
    __syncthreads();
    const float inv = 1.0f / (red[0] + red[1] + red[2] + red[3]);

    Wl[t] = e0 * inv;
    Wl[t + 256] = e1 * inv;
    __syncthreads();

    if (part == 2) {
        // store W for the scan + compute baseF column t
        W[i * V_ + t] = Wl[t];
        W[i * V_ + 256 + t] = Wl[t + 256];
        float acc = 0.0f;
        for (int v = 0; v < V_; ++v) acc += Wl[v] * vfs[v * DOUT_ + t];
        baseF[i * DOUT_ + t] = acc;
    } else {
        int d = part * 256 + t;
        if (d < DIN_) {
            float acc = 0.0f;
            for (int v = 0; v < V_; ++v) acc += Wl[v] * vu[v * DIN_ + d];
            baseH[i * DIN_ + d] = acc;
        }
    }
}

// ---------------- kernel 2: fused scan (blocks 0..B-1) + plane copy ----------------
// grid = B_ + DEPTH_*B_*4. Scan blocks come FIRST so they're resident
// immediately; the 4096 copy blocks saturate write BW concurrently, hiding
// the latency-bound scan under the 1.07 GB streaming write of `hold`.
__global__ void __launch_bounds__(256)
k_main(const float* __restrict__ inp, const float* __restrict__ vu,
       const float* __restrict__ vfs, const float* __restrict__ biases,
       const float* __restrict__ W, const float* __restrict__ baseH,
       const float* __restrict__ baseF,
       float* __restrict__ out, float* __restrict__ sel,
       float* __restrict__ lasth, int* __restrict__ idxh_g,
       float* __restrict__ hold) {
    const int t = threadIdx.x;

    if (blockIdx.x >= B_) {
        // ---- plane-copy role: hold[p] = vu (write-once; nt stores skip L2) ----
        const int cb = blockIdx.x - B_;
        const int CH = 4;
        const int F4_PER_PLANE = (V_ * DIN_) / 4;   // 65408
        const int F4_PER_CHUNK = F4_PER_PLANE / CH; // 16352
        const int p = cb / CH, c = cb % CH;
        const f32x4* __restrict__ src = (const f32x4*)vu;
        f32x4* __restrict__ dst = (f32x4*)hold + (size_t)p * F4_PER_PLANE;
        const int end = (c + 1) * F4_PER_CHUNK;
        #pragma unroll 4
        for (int k = c * F4_PER_CHUNK + t; k < end; k += 256) {
            f32x4 v = src[k];                       // vu stays L2-hot (reused 1024x)
            __builtin_nontemporal_store(v, &dst[k]);
        }
        return;
    }

    // ---- scan role: one block per batch row ----
    const int b = blockIdx.x;
    const int lane = t & 63, wid = t >> 6;

    __shared__ float iw[V_];
    __shared__ float Wl[V_];
    __shared__ float selh[DEPTH_][DIN_];
    __shared__ float fvals[DEPTH_][DOUT_];
    __shared__ float redf[4];
    __shared__ int   redi[4];
    __shared__ float bcv;
    __shared__ int   bci;
    __shared__ int   idxh[DEPTH_];

    // ---- build iw0 = [1 - sum(inp[b]), inp[b]] ----
    float x0 = inp[b * DIN_ + t];
    float x1 = (t < 255) ? inp[b * DIN_ + 256 + t] : 0.0f;
    float ssum = x0 + x1;
    #pragma unroll
    for (int off = 32; off; off >>= 1) ssum += __shfl_xor(ssum, off, 64);
    if (lane == 0) redf[wid] = ssum;
    iw[t + 1] = x0;                 // v = 1..256
    if (t < 255) iw[t + 257] = x1;  // v = 257..511
    __syncthreads();
    if (t == 0) iw[0] = 1.0f - (redf[0] + redf[1] + redf[2] + redf[3]);
    __syncthreads();

    // ---- scan over DEPTH steps ----
    for (int i = 0; i < DEPTH_; ++i) {
        Wl[t] = W[i * V_ + t];
        Wl[t + 256] = W[i * V_ + 256 + t];
        __syncthreads();
        const float w0 = Wl[t], w1 = Wl[t + 256];

        // argmin of iw / (w + 1e-20), first-index tie-break (lexicographic min)
        float d0 = iw[t]       / (w0 + 1e-20f);
        float d1 = iw[t + 256] / (w1 + 1e-20f);
        float bv; int bi;
        if (d0 <= d1) { bv = d0; bi = t; } else { bv = d1; bi = t + 256; }
        #pragma unroll
        for (int off = 32; off; off >>= 1) {
            float ov = __shfl_xor(bv, off, 64);
            int   oi = __shfl_xor(bi, off, 64);
            if (ov < bv || (ov == bv && oi < bi)) { bv = ov; bi = oi; }
        }
        if (lane == 0) { redf[wid] = bv; redi[wid] = bi; }
        __syncthreads();
        if (t == 0) {
            float mv = redf[0]; int mi = redi[0];
            #pragma unroll
            for (int w = 1; w < 4; ++w) {
                float ov = redf[w]; int oi = redi[w];
                if (ov < mv || (ov == mv && oi < mi)) { mv = ov; mi = oi; }
            }
            bcv = mv; bci = mi; idxh[i] = mi;
        }
        __syncthreads();
        const float mval = bcv;
        const int   midx = bci;

        // iw update: iw -= mval * w (all v), then iw[midx] = mval
        iw[t]       -= mval * w0;
        iw[t + 256] -= mval * w1;
        __syncthreads();
        if (t == 0) iw[midx] = mval;
        // (corrections below don't read iw; end-of-step barrier publishes it)

        // new_h = baseH[i] + corrections over live replaced rows (j < i)
        for (int d = t; d < DIN_; d += 256) {
            float acc = baseH[i * DIN_ + d];
            for (int j = 0; j < i; ++j) {
                int r = idxh[j];
                bool alive = true;
                for (int j2 = j + 1; j2 < i; ++j2)
                    if (idxh[j2] == r) { alive = false; break; }
                if (alive) acc += Wl[r] * (selh[j][d] - vu[r * DIN_ + d]);
            }
            selh[i][d] = acc;
            sel[(size_t)(i * B_ + b) * DIN_ + d] = acc;
        }
        // new_f = baseF[i] + bias[i] + corrections
        {
            float acc = baseF[i * DOUT_ + t] + biases[i * DOUT_ + t];
            for (int j = 0; j < i; ++j) {
                int r = idxh[j];
                bool alive = true;
                for (int j2 = j + 1; j2 < i; ++j2)
                    if (idxh[j2] == r) { alive = false; break; }
                if (alive) acc += Wl[r] * (fvals[j][t] - vfs[r * DOUT_ + t]);
            }
            fvals[i][t] = acc;
        }
        __syncthreads();
    }

    // ---- final out[b] = iw_final . f_final ----
    {
        float acc = 0.0f;
        #pragma unroll 8
        for (int v = 0; v < V_; ++v) acc += iw[v] * vfs[v * DOUT_ + t];
        #pragma unroll
        for (int j = 0; j < DEPTH_; ++j) {
            int r = idxh[j];
            bool alive = true;
            for (int j2 = j + 1; j2 < DEPTH_; ++j2)
                if (idxh[j2] == r) { alive = false; break; }
            if (alive) acc += iw[r] * (fvals[j][t] - vfs[r * DOUT_ + t]);
        }
        out[b * DOUT_ + t] = acc;
    }
    // last_h = selh[DEPTH-1]
    for (int d = t; d < DIN_; d += 256)
        lasth[b * DIN_ + d] = selh[DEPTH_ - 1][d];
    // export idx history for k_fixrows
    if (t < DEPTH_) idxh_g[b * DEPTH_ + t] = idxh[t];
}

// ---------------- kernel 3: overwrite replaced rows in h_old_stack ----------------
// grid = DEPTH*B planes, 128 threads. Tiny traffic (~7 MB), depends on scan.
__global__ void __launch_bounds__(128)
k_fixrows(const float* __restrict__ sel, const int* __restrict__ idxh_g,
          float* __restrict__ hold) {
    const int p = blockIdx.x;        // i*B + b
    const int i = p >> 7;            // / 128
    const int b = p & 127;
    const int t = threadIdx.x;
    for (int j = 0; j < i; ++j) {
        int r = idxh_g[b * DEPTH_ + j];
        bool alive = true;
        for (int j2 = j + 1; j2 < i; ++j2)
            if (idxh_g[b * DEPTH_ + j2] == r) { alive = false; break; }
        if (!alive) continue;
        const float* __restrict__ src = sel + (size_t)(j * B_ + b) * DIN_;
        float* __restrict__ dst = hold + ((size_t)p * V_ + r) * DIN_;
        for (int d = t; d < DIN_; d += 128) dst[d] = src[d];
    }
}

extern "C" void kernel_launch(void* const* d_in, const int* in_sizes, int n_in,
                              void* d_out, int out_size, void* d_ws, size_t ws_size,
                              hipStream_t stream) {
    const float* inp    = (const float*)d_in[0];  // (B, DIN)
    const float* vu     = (const float*)d_in[1];  // (V, DIN)
    const float* L      = (const float*)d_in[2];  // (DEPTH, V)
    const float* vfs    = (const float*)d_in[3];  // (V, DOUT)
    const float* biases = (const float*)d_in[4];  // (DEPTH, DOUT)

    float* out   = (float*)d_out;                                  // (B,1,DOUT)
    float* hold  = out + (size_t)B_ * DOUT_;                       // (DEPTH,B,V,DIN)
    float* sel   = hold + (size_t)DEPTH_ * B_ * V_ * DIN_;         // (DEPTH,B,DIN)
    float* lasth = sel + (size_t)DEPTH_ * B_ * DIN_;               // (B,DIN)

    float* W     = (float*)d_ws;                  // DEPTH*V
    float* baseH = W + DEPTH_ * V_;               // DEPTH*DIN
    float* baseF = baseH + DEPTH_ * DIN_;         // DEPTH*DOUT
    int*   idxh  = (int*)(baseF + DEPTH_ * DOUT_);// B*DEPTH

    k_prep<<<DEPTH_ * 3, 256, 0, stream>>>(L, vu, vfs, W, baseH, baseF);
    k_main<<<B_ + DEPTH_ * B_ * 4, 256, 0, stream>>>(inp, vu, vfs, biases,
                                                     W, baseH, baseF,
                                                     out, sel, lasth, idxh, hold);
    k_fixrows<<<DEPTH_ * B_, 128, 0, stream>>>(sel, idxh, hold);
}